// Round 4
// baseline (79.432 us; speedup 1.0000x reference)
//
#include <hip/hip_runtime.h>
#include <math.h>

#define NB 16
#define NC 256
#define NH 64
#define NW 64
#define HALF 128
#define PLANE (NH*NW)   // 4096

#define PP 4                 // channel pairs per block
#define PGROUPS (HALF/PP)    // 32

// ws float layout
#define WS_WW   0       // 256 floats: softmax(dir_weight_w)
#define WS_WH   256     // 256 floats: softmax(dir_weight_h)
#define WS_GH   512     // NB*NH = 1024
#define WS_GW   1536    // NB*NW = 1024
#define WS_CONS 2560    // NB*NH*NW = 65536
#define WS_ATT  68096   // NB*NH*NW = 65536
#define WS_TOTAL 133632

// blocks 0..65: zero gh/gw/cons (66*256 float4 = 67584 floats exactly).
// block 66: compute both channel softmaxes.
__global__ __launch_bounds__(256) void k_init(const float* __restrict__ dwh,
                                              const float* __restrict__ dww,
                                              float* __restrict__ ws) {
    const int t = threadIdx.x;
    if (blockIdx.x < 66) {
        float4 z = {0.f, 0.f, 0.f, 0.f};
        reinterpret_cast<float4*>(ws + WS_GH)[blockIdx.x * 256 + t] = z;
        return;
    }
    __shared__ float red[256];
    const float vh = dwh[t];
    const float vw = dww[t];

    red[t] = vw; __syncthreads();
    for (int s = 128; s > 0; s >>= 1) { if (t < s) red[t] = fmaxf(red[t], red[t+s]); __syncthreads(); }
    const float mw = red[0]; __syncthreads();
    const float ew = expf(vw - mw);
    red[t] = ew; __syncthreads();
    for (int s = 128; s > 0; s >>= 1) { if (t < s) red[t] += red[t+s]; __syncthreads(); }
    const float sw = red[0]; __syncthreads();
    ws[WS_WW + t] = ew / sw;

    red[t] = vh; __syncthreads();
    for (int s = 128; s > 0; s >>= 1) { if (t < s) red[t] = fmaxf(red[t], red[t+s]); __syncthreads(); }
    const float mh = red[0]; __syncthreads();
    const float eh = expf(vh - mh);
    red[t] = eh; __syncthreads();
    for (int s = 128; s > 0; s >>= 1) { if (t < s) red[t] += red[t+s]; __syncthreads(); }
    const float sh = red[0]; __syncthreads();
    ws[WS_WH + t] = eh / sh;
}

__device__ __forceinline__ float sum4(float4 v) { return (v.x+v.y)+(v.z+v.w); }

// Block = (b, group of PP channel pairs), covering the FULL 64x64 plane.
// Thread t: rg = t>>4 owns output rows 4rg..4rg+3; fc = t&15 owns cols 4fc..4fc+3.
// Separable 3x3 box: vertical 3-tap in registers (thread loads rows 4rg-1..4rg+4),
// horizontal 3-tap via 2 lane-shuffles per row. NO LDS / barriers in the hot loop.
__global__ __launch_bounds__(256) void k_reduce(const float* __restrict__ x,
                                                float* __restrict__ ws) {
    __shared__ float4 scol[256];   // gw staging (used once, after the loop)

    const int t  = threadIdx.x;
    const int rg = t >> 4;
    const int fc = t & 15;
    const int r0 = rg << 2;

    const int blk = blockIdx.x;
    const int b   = blk >> 5;      // / PGROUPS
    const int pg  = blk & (PGROUPS - 1);

    const float* wsw = ws + WS_WW;
    const float* wsh = ws + WS_WH;

    float4 c4[4] = {{0,0,0,0},{0,0,0,0},{0,0,0,0},{0,0,0,0}};
    float  ghrow[4] = {0.f, 0.f, 0.f, 0.f};
    float4 colacc = {0.f, 0.f, 0.f, 0.f};

    const float km0 = (rg == 0)  ? 0.f : 1.f;   // row -1 zero-pad
    const float km5 = (rg == 15) ? 0.f : 1.f;   // row 64 zero-pad

    #pragma unroll
    for (int pp = 0; pp < PP; ++pp) {
        const int c1 = pg * PP + pp;
        const int c2 = c1 + HALF;
        const float ww1 = wsw[c1], ww2 = wsw[c2];
        const float wh1 = wsh[c1], wh2 = wsh[c2];
        const float* p1 = x + ((size_t)(b*NC + c1)) * PLANE;
        const float* p2 = x + ((size_t)(b*NC + c2)) * PLANE;

        // load rows r0-1 .. r0+4 (clamped; out-of-range masked later), cols 4fc..4fc+3
        float4 a[6], bb[6];
        #pragma unroll
        for (int j = 0; j < 6; ++j) {
            int r = r0 - 1 + j;
            r = (r < 0) ? 0 : (r > 63 ? 63 : r);
            a[j]  = *(reinterpret_cast<const float4*>(p1 + r*NW) + fc);
            bb[j] = *(reinterpret_cast<const float4*>(p2 + r*NW) + fc);
        }

        // gh / gw contributions from owned rows (j = 1..4 -> rows r0..r0+3)
        #pragma unroll
        for (int j = 1; j <= 4; ++j) {
            ghrow[j-1] += ww1 * sum4(a[j]) + ww2 * sum4(bb[j]);
            colacc.x += wh1*a[j].x + wh2*bb[j].x;
            colacc.y += wh1*a[j].y + wh2*bb[j].y;
            colacc.z += wh1*a[j].z + wh2*bb[j].z;
            colacc.w += wh1*a[j].w + wh2*bb[j].w;
        }

        // products, with zero-pad masking for rows -1 / 64
        float4 p[6];
        #pragma unroll
        for (int j = 0; j < 6; ++j) {
            p[j].x = a[j].x*bb[j].x; p[j].y = a[j].y*bb[j].y;
            p[j].z = a[j].z*bb[j].z; p[j].w = a[j].w*bb[j].w;
        }
        p[0].x *= km0; p[0].y *= km0; p[0].z *= km0; p[0].w *= km0;
        p[5].x *= km5; p[5].y *= km5; p[5].z *= km5; p[5].w *= km5;

        // vertical 3-tap (registers) then horizontal 3-tap (2 shuffles/row)
        #pragma unroll
        for (int i = 0; i < 4; ++i) {
            float4 v;
            v.x = p[i].x + p[i+1].x + p[i+2].x;
            v.y = p[i].y + p[i+1].y + p[i+2].y;
            v.z = p[i].z + p[i+1].z + p[i+2].z;
            v.w = p[i].w + p[i+1].w + p[i+2].w;
            float L = __shfl_up(v.w, 1);
            float R = __shfl_down(v.x, 1);
            if (fc == 0)  L = 0.f;   // w = -1 zero-pad
            if (fc == 15) R = 0.f;   // w = 64 zero-pad
            c4[i].x += fabsf(L   + v.x + v.y);
            c4[i].y += fabsf(v.x + v.y + v.z);
            c4[i].z += fabsf(v.y + v.z + v.w);
            c4[i].w += fabsf(v.z + v.w + R);
        }
    }

    float* gh   = ws + WS_GH;
    float* gw   = ws + WS_GW;
    float* cons = ws + WS_CONS;

    // gh: reduce each owned row over the 16 fc lanes
    #pragma unroll
    for (int k = 0; k < 4; ++k) {
        float s = ghrow[k];
        s += __shfl_xor(s, 1); s += __shfl_xor(s, 2);
        s += __shfl_xor(s, 4); s += __shfl_xor(s, 8);
        if (fc == 0) atomicAdd(&gh[b*NH + r0 + k], s * (1.0f/16384.0f));
    }

    // gw: reduce colacc over the 16 row-groups via LDS
    scol[t] = colacc;
    __syncthreads();
    if (t < 64) {
        const float* sf = reinterpret_cast<const float*>(scol);
        float s = 0.f;
        #pragma unroll
        for (int g = 0; g < 16; ++g) s += sf[g*64 + t];
        atomicAdd(&gw[b*NW + t], s * (1.0f/16384.0f));
    }

    // cons: 16 per-pixel accumulators per thread
    const float SC = 1.0f / (9.0f * 128.0f);
    #pragma unroll
    for (int i = 0; i < 4; ++i) {
        float* cp = &cons[((size_t)(b*NH) + r0 + i)*NW + (fc << 2)];
        atomicAdd(cp + 0, c4[i].x * SC);
        atomicAdd(cp + 1, c4[i].y * SC);
        atomicAdd(cp + 2, c4[i].z * SC);
        atomicAdd(cp + 3, c4[i].w * SC);
    }
}

// attention map: one value per pixel (computed once, not once per channel)
__global__ __launch_bounds__(256) void k_att(float* __restrict__ ws,
                                             const float* __restrict__ pgw,
                                             const float* __restrict__ pgb) {
    const int pix = blockIdx.x * 256 + threadIdx.x;   // 0..65535
    const int b = pix >> 12, h = (pix >> 6) & 63, w = pix & 63;
    const float ghv = ws[WS_GH + b*NH + h];
    const float gwv = ws[WS_GW + b*NW + w];
    const float cv  = ws[WS_CONS + pix];
    const float anomaly = 1.f - fminf(fmaxf(cv, 0.f), 1.f);
    const float z = pgw[0] * (ghv + gwv) * anomaly + pgb[0];
    ws[WS_ATT + pix] = 1.f / (1.f + expf(-z));
}

__global__ __launch_bounds__(256) void k_apply(const float* __restrict__ x,
                                               const float* __restrict__ ws,
                                               float* __restrict__ out) {
    const float* att = ws + WS_ATT;
    const int total4 = NB*NC*NH*NW/4;   // 4,194,304
    const int stride = gridDim.x * blockDim.x;
    for (int i = blockIdx.x*blockDim.x + threadIdx.x; i < total4; i += stride) {
        const int w4 = i & 15;           // w/4
        const int h  = (i >> 4) & 63;
        const int b  = i >> 18;
        const float4 xv = reinterpret_cast<const float4*>(x)[i];
        const float4 av = reinterpret_cast<const float4*>(att)[(b << 10) + (h << 4) + w4];
        float4 o;
        o.x = xv.x * av.x; o.y = xv.y * av.y;
        o.z = xv.z * av.z; o.w = xv.w * av.w;
        reinterpret_cast<float4*>(out)[i] = o;
    }
}

extern "C" void kernel_launch(void* const* d_in, const int* in_sizes, int n_in,
                              void* d_out, int out_size, void* d_ws, size_t ws_size,
                              hipStream_t stream) {
    const float* x   = (const float*)d_in[0];
    const float* dwh = (const float*)d_in[1];
    const float* dww = (const float*)d_in[2];
    const float* pgw = (const float*)d_in[3];
    const float* pgb = (const float*)d_in[4];
    float* out = (float*)d_out;
    float* ws  = (float*)d_ws;

    k_init<<<67, 256, 0, stream>>>(dwh, dww, ws);
    k_reduce<<<NB*PGROUPS, 256, 0, stream>>>(x, ws);
    k_att<<<256, 256, 0, stream>>>(ws, pgw, pgb);
    k_apply<<<2048, 256, 0, stream>>>(x, ws, out);
}

// Round 5
// 67.799 us; speedup vs baseline: 1.1716x; 1.1716x over previous
//
#include <hip/hip_runtime.h>
#include <math.h>

#define NB 16
#define NC 256
#define NH 64
#define NW 64
#define HALF 128
#define PLANE (NH*NW)   // 4096

#define NPG 32           // channel-pair groups (4 pairs each) -> partial slices

// ws float layout (small; partials live in d_out scratch)
#define WS_WW   0       // 256
#define WS_WH   256     // 256
#define WS_GH   512     // NB*NH = 1024
#define WS_GW   1536    // NB*NW = 1024
#define WS_ATT  2560    // NB*NH*NW = 65536
#define WS_TOTAL 68096

__device__ __forceinline__ float sum4(float4 v) { return (v.x+v.y)+(v.z+v.w); }

// blocks 0,1: zero gh/gw (512 float4). block 2: both channel softmaxes.
__global__ __launch_bounds__(256) void k_init(const float* __restrict__ dwh,
                                              const float* __restrict__ dww,
                                              float* __restrict__ ws) {
    const int t = threadIdx.x;
    if (blockIdx.x < 2) {
        float4 z = {0.f,0.f,0.f,0.f};
        reinterpret_cast<float4*>(ws + WS_GH)[blockIdx.x*256 + t] = z;
        return;
    }
    __shared__ float red[256];
    const float vh = dwh[t];
    const float vw = dww[t];

    red[t] = vw; __syncthreads();
    for (int s = 128; s > 0; s >>= 1) { if (t < s) red[t] = fmaxf(red[t], red[t+s]); __syncthreads(); }
    const float mw = red[0]; __syncthreads();
    const float ew = expf(vw - mw);
    red[t] = ew; __syncthreads();
    for (int s = 128; s > 0; s >>= 1) { if (t < s) red[t] += red[t+s]; __syncthreads(); }
    const float sw = red[0]; __syncthreads();
    ws[WS_WW + t] = ew / sw;

    red[t] = vh; __syncthreads();
    for (int s = 128; s > 0; s >>= 1) { if (t < s) red[t] = fmaxf(red[t], red[t+s]); __syncthreads(); }
    const float mh = red[0]; __syncthreads();
    const float eh = expf(vh - mh);
    red[t] = eh; __syncthreads();
    for (int s = 128; s > 0; s >>= 1) { if (t < s) red[t] += red[t+s]; __syncthreads(); }
    const float sh = red[0]; __syncthreads();
    ws[WS_WH + t] = eh / sh;
}

// Block = (b, 16-row stripe, group of 4 channel pairs). 2048 blocks.
// Thread t = pl(2b)|rg(2b)|fc(4b): ONE channel pair, 4 rows x 4 cols.
// 12 independent float4 loads/thread, zero barriers in compute phase.
// cons partials -> d_out scratch (non-atomic); gh/gw via atomics.
__global__ __launch_bounds__(256) void k_reduce(const float* __restrict__ x,
                                                float* __restrict__ ws,
                                                float* __restrict__ part) {
    __shared__ float lds[4096];   // 16 KB

    const int t  = threadIdx.x;
    const int pl = t >> 6;         // pair lane 0..3 (wave-uniform)
    const int rg = (t >> 4) & 3;   // row group 0..3
    const int fc = t & 15;         // float4 col 0..15

    const int blk    = blockIdx.x;
    const int pg     = blk & 31;
    const int stripe = (blk >> 5) & 3;
    const int b      = blk >> 7;

    const int c1 = pg*4 + pl;
    const int c2 = c1 + HALF;
    const int r0 = stripe*16 + rg*4;     // global first owned row

    const float ww1 = ws[WS_WW + c1], ww2 = ws[WS_WW + c2];
    const float wh1 = ws[WS_WH + c1], wh2 = ws[WS_WH + c2];

    const float* p1 = x + ((size_t)(b*NC + c1)) * PLANE;
    const float* p2 = x + ((size_t)(b*NC + c2)) * PLANE;

    // rows r0-1 .. r0+4 (clamped at plane edges; masked below)
    float4 a[6], bb[6];
    #pragma unroll
    for (int j = 0; j < 6; ++j) {
        int r = r0 - 1 + j;
        r = (r < 0) ? 0 : (r > 63 ? 63 : r);
        a[j]  = *(reinterpret_cast<const float4*>(p1 + r*NW) + fc);
        bb[j] = *(reinterpret_cast<const float4*>(p2 + r*NW) + fc);
    }

    // gh / gw contributions from owned rows
    float ghrow[4];
    float4 colacc = {0.f,0.f,0.f,0.f};
    #pragma unroll
    for (int j = 1; j <= 4; ++j) {
        ghrow[j-1] = ww1*sum4(a[j]) + ww2*sum4(bb[j]);
        colacc.x += wh1*a[j].x + wh2*bb[j].x;
        colacc.y += wh1*a[j].y + wh2*bb[j].y;
        colacc.z += wh1*a[j].z + wh2*bb[j].z;
        colacc.w += wh1*a[j].w + wh2*bb[j].w;
    }

    // products with zero-pad masks at global top/bottom
    const float km0 = (r0 == 0)  ? 0.f : 1.f;
    const float km5 = (r0 == 60) ? 0.f : 1.f;
    float4 p[6];
    #pragma unroll
    for (int j = 0; j < 6; ++j) {
        p[j].x = a[j].x*bb[j].x; p[j].y = a[j].y*bb[j].y;
        p[j].z = a[j].z*bb[j].z; p[j].w = a[j].w*bb[j].w;
    }
    p[0].x *= km0; p[0].y *= km0; p[0].z *= km0; p[0].w *= km0;
    p[5].x *= km5; p[5].y *= km5; p[5].z *= km5; p[5].w *= km5;

    // vertical 3-tap in registers, horizontal 3-tap via 2 shuffles/row
    float4 c4[4];
    #pragma unroll
    for (int i = 0; i < 4; ++i) {
        float4 v;
        v.x = p[i].x + p[i+1].x + p[i+2].x;
        v.y = p[i].y + p[i+1].y + p[i+2].y;
        v.z = p[i].z + p[i+1].z + p[i+2].z;
        v.w = p[i].w + p[i+1].w + p[i+2].w;
        float L = __shfl_up(v.w, 1);
        float R = __shfl_down(v.x, 1);
        if (fc == 0)  L = 0.f;
        if (fc == 15) R = 0.f;
        c4[i].x = fabsf(L   + v.x + v.y);
        c4[i].y = fabsf(v.x + v.y + v.z);
        c4[i].z = fabsf(v.y + v.z + v.w);
        c4[i].w = fabsf(v.z + v.w + R);
    }

    // gh: reduce over the 16 fc lanes of each (pl, rg) group
    float* gh = ws + WS_GH;
    float* gw = ws + WS_GW;
    #pragma unroll
    for (int k = 0; k < 4; ++k) {
        float s = ghrow[k];
        s += __shfl_xor(s, 1); s += __shfl_xor(s, 2);
        s += __shfl_xor(s, 4); s += __shfl_xor(s, 8);
        if (fc == 0) atomicAdd(&gh[b*NH + r0 + k], s * (1.0f/16384.0f));
    }

    // cons: reduce across the 4 pair-lanes via LDS, write partial plane
    #pragma unroll
    for (int i = 0; i < 4; ++i) {
        lds[t*16 + i*4 + 0] = c4[i].x;
        lds[t*16 + i*4 + 1] = c4[i].y;
        lds[t*16 + i*4 + 2] = c4[i].z;
        lds[t*16 + i*4 + 3] = c4[i].w;
    }
    __syncthreads();
    {
        const int lh  = t >> 4;          // local row 0..15
        const int rg2 = lh >> 2, i2 = lh & 3;
        const int fc2 = t & 15;
        float4 s = {0.f,0.f,0.f,0.f};
        #pragma unroll
        for (int q = 0; q < 4; ++q) {
            const float* e = &lds[((q*4 + rg2)*16 + fc2)*16 + i2*4];
            s.x += e[0]; s.y += e[1]; s.z += e[2]; s.w += e[3];
        }
        const float SC = 1.0f/(9.0f*128.0f);
        s.x *= SC; s.y *= SC; s.z *= SC; s.w *= SC;
        // slice layout: part[pg][b][stripe][16x64] -> pixel-linear within pg
        float4* dst = reinterpret_cast<float4*>(part) + ((size_t)pg << 14) + ((b*4 + stripe) << 8);
        dst[t] = s;
    }

    // gw: reduce colacc over 16 (pl,rg) groups via LDS
    __syncthreads();
    reinterpret_cast<float4*>(lds)[t] = colacc;
    __syncthreads();
    if (t < 64) {
        float s = 0.f;
        #pragma unroll
        for (int pr = 0; pr < 16; ++pr) s += lds[pr*64 + t];
        atomicAdd(&gw[b*NW + t], s * (1.0f/16384.0f));
    }
}

// attention map: sum 32 cons partials + gh + gw -> sigmoid, once per pixel
__global__ __launch_bounds__(256) void k_att(float* __restrict__ ws,
                                             const float* __restrict__ part,
                                             const float* __restrict__ pgw,
                                             const float* __restrict__ pgb) {
    const int u  = blockIdx.x*256 + threadIdx.x;   // float4-pixel 0..16383
    const int b  = u >> 10;
    const int h  = (u >> 4) & 63;
    const int w4 = u & 15;

    const float4* pp = reinterpret_cast<const float4*>(part);
    float4 s = {0.f,0.f,0.f,0.f};
    #pragma unroll
    for (int g = 0; g < NPG; ++g) {
        const float4 v = pp[(g << 14) + u];
        s.x += v.x; s.y += v.y; s.z += v.z; s.w += v.w;
    }
    const float ghv  = ws[WS_GH + b*NH + h];
    const float4 gwv = *reinterpret_cast<const float4*>(ws + WS_GW + b*NW + w4*4);
    const float gW = pgw[0], gB = pgb[0];

    float4 o;
    float z;
    z = gW*(ghv+gwv.x)*(1.f - fminf(fmaxf(s.x,0.f),1.f)) + gB; o.x = 1.f/(1.f+expf(-z));
    z = gW*(ghv+gwv.y)*(1.f - fminf(fmaxf(s.y,0.f),1.f)) + gB; o.y = 1.f/(1.f+expf(-z));
    z = gW*(ghv+gwv.z)*(1.f - fminf(fmaxf(s.z,0.f),1.f)) + gB; o.z = 1.f/(1.f+expf(-z));
    z = gW*(ghv+gwv.w)*(1.f - fminf(fmaxf(s.w,0.f),1.f)) + gB; o.w = 1.f/(1.f+expf(-z));
    reinterpret_cast<float4*>(ws + WS_ATT)[u] = o;
}

__global__ __launch_bounds__(256) void k_apply(const float* __restrict__ x,
                                               const float* __restrict__ ws,
                                               float* __restrict__ out) {
    const float* att = ws + WS_ATT;
    const int total4 = NB*NC*NH*NW/4;   // 4,194,304
    const int stride = gridDim.x * blockDim.x;
    for (int i = blockIdx.x*blockDim.x + threadIdx.x; i < total4; i += stride) {
        const int w4 = i & 15;
        const int h  = (i >> 4) & 63;
        const int b  = i >> 18;
        const float4 xv = reinterpret_cast<const float4*>(x)[i];
        const float4 av = reinterpret_cast<const float4*>(att)[(b << 10) + (h << 4) + w4];
        float4 o;
        o.x = xv.x*av.x; o.y = xv.y*av.y; o.z = xv.z*av.z; o.w = xv.w*av.w;
        reinterpret_cast<float4*>(out)[i] = o;
    }
}

extern "C" void kernel_launch(void* const* d_in, const int* in_sizes, int n_in,
                              void* d_out, int out_size, void* d_ws, size_t ws_size,
                              hipStream_t stream) {
    const float* x   = (const float*)d_in[0];
    const float* dwh = (const float*)d_in[1];
    const float* dww = (const float*)d_in[2];
    const float* pgw = (const float*)d_in[3];
    const float* pgb = (const float*)d_in[4];
    float* out = (float*)d_out;
    float* ws  = (float*)d_ws;
    // d_out doubles as scratch for cons partials (8 MB) -- written by k_reduce,
    // consumed by k_att, then fully overwritten by k_apply.
    float* part = out;

    k_init<<<3, 256, 0, stream>>>(dwh, dww, ws);
    k_reduce<<<NB*4*NPG, 256, 0, stream>>>(x, ws, part);
    k_att<<<64, 256, 0, stream>>>(ws, part, pgw, pgb);
    k_apply<<<2048, 256, 0, stream>>>(x, ws, out);
}